// Round 13
// baseline (244.237 us; speedup 1.0000x reference)
//
#include <hip/hip_runtime.h>
#include <hip/hip_bf16.h>

// B=2, S=4096, H=768, NH=12, HD=64
typedef float f32x4 __attribute__((ext_vector_type(4)));
typedef float f32x16 __attribute__((ext_vector_type(16)));
typedef short short8 __attribute__((ext_vector_type(8)));

#define LOG2E 1.44269504088896340736f

__device__ __forceinline__ ushort f2bf(float f){
  unsigned u = __builtin_bit_cast(unsigned, f);
  u = (u + 0x7fffu + ((u >> 16) & 1u)) >> 16;
  return (ushort)u;
}

__device__ __forceinline__ float exp2_hw(float x){
  float r; asm("v_exp_f32 %0, %1" : "=v"(r) : "v"(x)); return r;
}

// packed 2xf32 ops (VOP3P, operate on VGPR pairs)
__device__ __forceinline__ double pk_add(double a, double b){
  double d; asm("v_pk_add_f32 %0, %1, %2" : "=v"(d) : "v"(a), "v"(b)); return d;
}
__device__ __forceinline__ double pk_mul(double a, double b){
  double d; asm("v_pk_mul_f32 %0, %1, %2" : "=v"(d) : "v"(a), "v"(b)); return d;
}
__device__ __forceinline__ uint cvtpk_bf16(float lo, float hi){
  uint r; asm("v_cvt_pk_bf16_f32 %0, %1, %2" : "=v"(r) : "v"(lo), "v"(hi)); return r;
}
__device__ __forceinline__ double f2d(float x, float y){
  union { float f[2]; double d; } u; u.f[0] = x; u.f[1] = y; return u.d;
}
__device__ __forceinline__ float fmax3(float a, float b, float c){
  return fmaxf(fmaxf(a, b), c);   // clang fuses to v_max3_f32
}

union F16u { f32x16 v; double d[8]; float f[16]; };

__global__ void cvt_kernel(const float* __restrict__ src, ushort* __restrict__ dst, int n4){
  int i = blockIdx.x * 256 + threadIdx.x;
  if (i < n4){
    float4 v = ((const float4*)src)[i];
    ushort4 o; o.x = f2bf(v.x); o.y = f2bf(v.y); o.z = f2bf(v.z); o.w = f2bf(v.w);
    ((ushort4*)dst)[i] = o;
  }
}

__global__ void scale_kernel(const float* __restrict__ src, float* __restrict__ dst,
                             float sc, int n){
  int i = blockIdx.x * 256 + threadIdx.x;
  if (i < n) dst[i] = src[i] * sc;
}

// Fused QKV projection: one launch, grid (64, 18). blockIdx.y/6 selects {Q,K,V}.
__global__ __launch_bounds__(256) void qkv_fused(const ushort* __restrict__ Xb,
                                                 const ushort* __restrict__ Wqb,
                                                 const ushort* __restrict__ Wkb,
                                                 const ushort* __restrict__ Wvb,
                                                 const float* __restrict__ bqp,
                                                 const float* __restrict__ bkp,
                                                 const float* __restrict__ bvp,
                                                 ushort* __restrict__ Qo,
                                                 ushort* __restrict__ Ko,
                                                 ushort* __restrict__ Vto,
                                                 float qscale){
  __shared__ ushort Xs[128*64];
  __shared__ ushort Ws[128*64];
  const int sel = blockIdx.y / 6;
  const int m0 = blockIdx.x * 128, n0 = (blockIdx.y % 6) * 128;
  const ushort* Wb  = (sel == 0) ? Wqb : (sel == 1) ? Wkb : Wvb;
  const float* bias = (sel == 0) ? bqp : (sel == 1) ? bkp : bvp;
  const int tid = threadIdx.x, w = tid >> 6, lane = tid & 63;
  const int r = lane & 15, g = lane >> 4;
  const int wr = (w >> 1) * 64, wc = (w & 1) * 64;
  const int lrow = lane >> 3;
  const int gk = (lane & 7) ^ lrow;
  f32x4 acc[4][4] = {};
  for (int k0 = 0; k0 < 768; k0 += 64){
    #pragma unroll
    for (int p = 0; p < 4; p++){
      int rowb = p*32 + w*8;
      int row = rowb + lrow;
      __builtin_amdgcn_global_load_lds(
        (const uint4*)(Xb + (size_t)(m0+row)*768 + k0 + gk*8),
        (uint4*)((char*)Xs + rowb*128), 16, 0, 0);
      __builtin_amdgcn_global_load_lds(
        (const uint4*)(Wb + (size_t)(n0+row)*768 + k0 + gk*8),
        (uint4*)((char*)Ws + rowb*128), 16, 0, 0);
    }
    __syncthreads();
    #pragma unroll
    for (int ks = 0; ks < 2; ks++){
      short8 af[4], bf[4];
      int bo = ks*64 + g*16;
      #pragma unroll
      for (int i = 0; i < 4; i++){
        int rowa = wr + i*16 + r;
        af[i] = *(const short8*)((char*)Xs + rowa*128 + (bo ^ ((rowa&7)<<4)));
        int rowb2 = wc + i*16 + r;
        bf[i] = *(const short8*)((char*)Ws + rowb2*128 + (bo ^ ((rowb2&7)<<4)));
      }
      #pragma unroll
      for (int i = 0; i < 4; i++)
        #pragma unroll
        for (int j = 0; j < 4; j++)
          acc[i][j] = __builtin_amdgcn_mfma_f32_16x16x32_bf16(af[i], bf[j], acc[i][j], 0,0,0);
    }
    __syncthreads();
  }
  if (sel < 2){
    ushort* Out = sel ? Ko : Qo;
    float scale = sel ? 1.0f : qscale;
    #pragma unroll
    for (int i = 0; i < 4; i++){
      #pragma unroll
      for (int j = 0; j < 4; j++){
        int col = n0 + wc + j*16 + r;
        float bv = bias[col];
        int rowb = m0 + wr + i*16 + g*4;
        #pragma unroll
        for (int q = 0; q < 4; q++)
          Out[(size_t)(rowb+q)*768 + col] = f2bf((acc[i][j][q] + bv) * scale);
      }
    }
  } else {
    #pragma unroll
    for (int i = 0; i < 4; i++){
      #pragma unroll
      for (int j = 0; j < 4; j++){
        int col = n0 + wc + j*16 + r;
        float bv = bias[col];
        int rowb = m0 + wr + i*16 + g*4;
        ushort4 o;
        o.x = f2bf(acc[i][j][0] + bv);
        o.y = f2bf(acc[i][j][1] + bv);
        o.z = f2bf(acc[i][j][2] + bv);
        o.w = f2bf(acc[i][j][3] + bv);
        size_t vrow = (size_t)((rowb >> 12) * 768 + col);
        *(ushort4*)(Vto + vrow * 4096 + (rowb & 4095)) = o;
      }
    }
  }
}

// Flash attention, split-KV x2, SINGLE-BUFFERED 16KB LDS (K@0, V@8192),
// two barriers per tile. Math core identical to R10/R12 (proven).
__global__ __launch_bounds__(256, 3) void flash_attn(const ushort* __restrict__ Qb,
                                                     const ushort* __restrict__ Kb,
                                                     const ushort* __restrict__ Vt,
                                                     const float* __restrict__ maskL,
                                                     float* __restrict__ part0,
                                                     float* __restrict__ part1,
                                                     float2* __restrict__ lm){
  __shared__ ushort SMEM[8192];  // 16KB: K@0 (8KB), V@8192 (8KB)
  const int tid = threadIdx.x, w = tid >> 6, lane = tid & 63;
  const int q = lane & 31, hi = lane >> 5;
  const int swq = (q & 7) << 4;
  const int h = blockIdx.y, b = blockIdx.z;
  const int qt = blockIdx.x >> 1, half = blockIdx.x & 1;
  const int q0 = qt * 128 + w * 32;
  char* sm = (char*)SMEM;

  short8 bq[4];
  {
    const ushort* qp = Qb + (size_t)(b*4096 + q0 + q)*768 + h*64 + hi*8;
    #pragma unroll
    for (int kd = 0; kd < 4; kd++) bq[kd] = *(const short8*)(qp + 16*kd);
  }
  const ushort* Kbase = Kb + (size_t)(b*4096 + half*2048)*768 + h*64;
  const ushort* Vbase = Vt + (size_t)(b*768 + h*64)*4096 + half*2048;

  const int row0 = tid >> 3, cir = tid & 7;
  const int row1 = row0 + 32;
  const int wb0 = row0*128 + ((cir*16) ^ ((row0&7)<<4));
  const int wb1 = row1*128 + ((cir*16) ^ ((row1&7)<<4));
  const ushort* kp0 = Kbase + (size_t)row0*768 + cir*8;
  const ushort* kp1 = Kbase + (size_t)row1*768 + cir*8;
  const ushort* vp0 = Vbase + (size_t)row0*4096 + cir*8;
  const ushort* vp1 = Vbase + (size_t)row1*4096 + cir*8;

  int off4[4];
  #pragma unroll
  for (int kd = 0; kd < 4; kd++)
    off4[kd] = q*128 + ((32*kd + 16*hi) ^ swq);

  // prologue: tile 0 -> regs
  uint4 k0r = *(const uint4*)kp0, k1r = *(const uint4*)kp1;
  uint4 v0r = *(const uint4*)vp0, v1r = *(const uint4*)vp1;

  F16u c0, c1;
  { f32x16 zz = {}; c0.v = zz; c1.v = zz; }
  float mrun = -1e30f, lrun = 0.f;

  for (int t = 0; t < 32; t++){
    if (t > 0) __syncthreads();           // readers of tile t-1 done
    // stage tile t (regs -> LDS)
    *(uint4*)(sm + wb0) = k0r;            *(uint4*)(sm + wb1) = k1r;
    *(uint4*)(sm + 8192 + wb0) = v0r;     *(uint4*)(sm + 8192 + wb1) = v1r;
    // issue loads for tile t+1 (latency hides under compute below)
    if (t < 31){
      const size_t kn = (size_t)(t+1) * 64;
      k0r = *(const uint4*)(kp0 + kn*768);
      k1r = *(const uint4*)(kp1 + kn*768);
      v0r = *(const uint4*)(vp0 + kn);
      v1r = *(const uint4*)(vp1 + kn);
    }
    __syncthreads();                      // staged writes visible
    // QK^T
    __builtin_amdgcn_s_setprio(1);
    f32x16 z0 = {}, z1 = {};
    #pragma unroll
    for (int kd = 0; kd < 4; kd++){
      short8 ak = *(const short8*)(sm + off4[kd]);
      z0 = __builtin_amdgcn_mfma_f32_32x32x16_bf16(ak, bq[kd], z0, 0,0,0);
    }
    #pragma unroll
    for (int kd = 0; kd < 4; kd++){
      short8 ak = *(const short8*)(sm + 4096 + off4[kd]);
      z1 = __builtin_amdgcn_mfma_f32_32x32x16_bf16(ak, bq[kd], z1, 0,0,0);
    }
    __builtin_amdgcn_s_setprio(0);
    F16u s0, s1; s0.v = z0; s1.v = z1;
    // + mask (log2-scaled), packed adds
    const float* mrow = maskL + b*4096 + half*2048 + t*64 + hi*4;
    #pragma unroll
    for (int eq = 0; eq < 4; eq++){
      float4 m0v = *(const float4*)(mrow + eq*8);
      s0.d[2*eq]   = pk_add(s0.d[2*eq],   f2d(m0v.x, m0v.y));
      s0.d[2*eq+1] = pk_add(s0.d[2*eq+1], f2d(m0v.z, m0v.w));
      float4 m1v = *(const float4*)(mrow + 32 + eq*8);
      s1.d[2*eq]   = pk_add(s1.d[2*eq],   f2d(m1v.x, m1v.y));
      s1.d[2*eq+1] = pk_add(s1.d[2*eq+1], f2d(m1v.z, m1v.w));
    }
    // max over 32 in-lane values + lane^32 exchange
    float ma = fmax3(s0.f[0], s0.f[1], s0.f[2]);
    float mb = fmax3(s0.f[3], s0.f[4], s0.f[5]);
    ma = fmax3(ma, s0.f[6], s0.f[7]);
    mb = fmax3(mb, s0.f[8], s0.f[9]);
    ma = fmax3(ma, s0.f[10], s0.f[11]);
    mb = fmax3(mb, s0.f[12], s0.f[13]);
    ma = fmax3(ma, s0.f[14], s0.f[15]);
    mb = fmax3(mb, s1.f[0], s1.f[1]);
    ma = fmax3(ma, s1.f[2], s1.f[3]);
    mb = fmax3(mb, s1.f[4], s1.f[5]);
    ma = fmax3(ma, s1.f[6], s1.f[7]);
    mb = fmax3(mb, s1.f[8], s1.f[9]);
    ma = fmax3(ma, s1.f[10], s1.f[11]);
    mb = fmax3(mb, s1.f[12], s1.f[13]);
    float mt = fmax3(ma, s1.f[14], fmaxf(mb, s1.f[15]));
    mt = fmaxf(mt, __shfl_xor(mt, 32, 64));
    // defer-max (THR = 8*log2e)
    if (!__all(mt <= mrun + 11.5415603f)){
      float mnew = fmaxf(mrun, mt);
      float alpha = exp2_hw(mrun - mnew);
      mrun = mnew;
      lrun *= alpha;
      double al2 = f2d(alpha, alpha);
      #pragma unroll
      for (int i = 0; i < 8; i++){
        c0.d[i] = pk_mul(c0.d[i], al2);
        c1.d[i] = pk_mul(c1.d[i], al2);
      }
    }
    // p = exp2(s - mrun)
    double msub = f2d(-mrun, -mrun);
    #pragma unroll
    for (int i = 0; i < 8; i++){
      s0.d[i] = pk_add(s0.d[i], msub);
      s1.d[i] = pk_add(s1.d[i], msub);
    }
    #pragma unroll
    for (int e = 0; e < 16; e++){
      s0.f[e] = exp2_hw(s0.f[e]);
      s1.f[e] = exp2_hw(s1.f[e]);
    }
    // row-sum via packed tree
    double t00 = pk_add(s0.d[0], s0.d[1]), t01 = pk_add(s0.d[2], s0.d[3]);
    double t02 = pk_add(s0.d[4], s0.d[5]), t03 = pk_add(s0.d[6], s0.d[7]);
    double t10 = pk_add(s1.d[0], s1.d[1]), t11 = pk_add(s1.d[2], s1.d[3]);
    double t12 = pk_add(s1.d[4], s1.d[5]), t13 = pk_add(s1.d[6], s1.d[7]);
    double u0 = pk_add(t00, t01), u1 = pk_add(t02, t03);
    double u2 = pk_add(t10, t11), u3 = pk_add(t12, t13);
    double wsum = pk_add(pk_add(u0, u1), pk_add(u2, u3));
    {
      union { double d; float f[2]; } uw; uw.d = wsum;
      float rs = uw.f[0] + uw.f[1];
      rs += __shfl_xor(rs, 32, 64);
      lrun += rs;
    }
    // pack P (cvt_pk) + permlane32_swap -> PV B-frags
    short8 bp[4];
    {
      uint pw[8];
      #pragma unroll
      for (int u = 0; u < 8; u++) pw[u] = cvtpk_bf16(s0.f[2*u], s0.f[2*u+1]);
      #pragma unroll
      for (int u2 = 0; u2 < 2; u2++){
        uint x0 = pw[4*u2+0], x1 = pw[4*u2+1], x2 = pw[4*u2+2], x3 = pw[4*u2+3];
        asm("v_permlane32_swap_b32 %0, %1" : "+v"(x0), "+v"(x2));
        asm("v_permlane32_swap_b32 %0, %1" : "+v"(x1), "+v"(x3));
        union { uint u[4]; short8 v; } bb;
        bb.u[0] = x0; bb.u[1] = x1; bb.u[2] = x2; bb.u[3] = x3;
        bp[u2] = bb.v;
      }
      #pragma unroll
      for (int u = 0; u < 8; u++) pw[u] = cvtpk_bf16(s1.f[2*u], s1.f[2*u+1]);
      #pragma unroll
      for (int u2 = 0; u2 < 2; u2++){
        uint x0 = pw[4*u2+0], x1 = pw[4*u2+1], x2 = pw[4*u2+2], x3 = pw[4*u2+3];
        asm("v_permlane32_swap_b32 %0, %1" : "+v"(x0), "+v"(x2));
        asm("v_permlane32_swap_b32 %0, %1" : "+v"(x1), "+v"(x3));
        union { uint u[4]; short8 v; } bb;
        bb.u[0] = x0; bb.u[1] = x1; bb.u[2] = x2; bb.u[3] = x3;
        bp[2+u2] = bb.v;
      }
    }
    // PV (V @ +8192, folds into ds_read immediates)
    __builtin_amdgcn_s_setprio(1);
    #pragma unroll
    for (int kk = 0; kk < 4; kk++){
      short8 av = *(const short8*)(sm + 8192 + off4[kk]);
      c0.v = __builtin_amdgcn_mfma_f32_32x32x16_bf16(av, bp[kk], c0.v, 0,0,0);
    }
    #pragma unroll
    for (int kk = 0; kk < 4; kk++){
      short8 av = *(const short8*)(sm + 8192 + 4096 + off4[kk]);
      c1.v = __builtin_amdgcn_mfma_f32_32x32x16_bf16(av, bp[kk], c1.v, 0,0,0);
    }
    __builtin_amdgcn_s_setprio(0);
  }
  // epilogue: write UNNORMALIZED partial ctx + (m,l)
  float* part = half ? part1 : part0;
  size_t orow = (size_t)(b*4096 + q0 + q) * 768 + h*64;
  #pragma unroll
  for (int eq = 0; eq < 4; eq++){
    float4 o;
    o.x = c0.f[4*eq+0]; o.y = c0.f[4*eq+1];
    o.z = c0.f[4*eq+2]; o.w = c0.f[4*eq+3];
    *(float4*)(part + orow + eq*8 + hi*4) = o;
  }
  #pragma unroll
  for (int eq = 0; eq < 4; eq++){
    float4 o;
    o.x = c1.f[4*eq+0]; o.y = c1.f[4*eq+1];
    o.z = c1.f[4*eq+2]; o.w = c1.f[4*eq+3];
    *(float4*)(part + orow + 32 + eq*8 + hi*4) = o;
  }
  if (hi == 0){
    int idx = ((half*2 + b)*12 + h)*4096 + (q0 + q);
    lm[idx] = make_float2(mrun, lrun);
  }
}

// O = (c0*e0 + c1*e1) / (l0*e0 + l1*e1), e_i = exp2(m_i - max(m0,m1)). In-place on c0.
__global__ void merge_kernel(float* __restrict__ c0, const float* __restrict__ c1,
                             const float2* __restrict__ lm){
  int i = blockIdx.x * 256 + threadIdx.x;     // float4 index
  const int nf4 = 2*4096*768/4;
  if (i >= nf4) return;
  int f = i * 4;
  int b = f / (4096*768);
  int rem = f - b*(4096*768);
  int qrow = rem / 768;
  int col = rem - qrow*768;
  int head = col >> 6;
  float2 L0 = lm[((    b)*12 + head)*4096 + qrow];
  float2 L1 = lm[((2 + b)*12 + head)*4096 + qrow];
  float M = fmaxf(L0.x, L1.x);
  float e0 = exp2f(L0.x - M), e1 = exp2f(L1.x - M);
  float inv = 1.0f / (L0.y*e0 + L1.y*e1);
  float4 a = ((const float4*)c0)[i];
  float4 bb = ((const float4*)c1)[i];
  float4 o;
  o.x = (a.x*e0 + bb.x*e1) * inv;
  o.y = (a.y*e0 + bb.y*e1) * inv;
  o.z = (a.z*e0 + bb.z*e1) * inv;
  o.w = (a.w*e0 + bb.w*e1) * inv;
  ((float4*)c0)[i] = o;
}

extern "C" void kernel_launch(void* const* d_in, const int* in_sizes, int n_in,
                              void* d_out, int out_size, void* d_ws, size_t ws_size,
                              hipStream_t stream){
  const float* hidden = (const float*)d_in[0];
  const float* mask   = (const float*)d_in[1];
  const float* Wq     = (const float*)d_in[2];
  const float* bq     = (const float*)d_in[3];
  const float* Wk     = (const float*)d_in[4];
  const float* bk     = (const float*)d_in[5];
  const float* Wv     = (const float*)d_in[6];
  const float* bv     = (const float*)d_in[7];
  char* ws = (char*)d_ws;
  ushort* Xb    = (ushort*)(ws);
  ushort* Wqb   = (ushort*)(ws + 12582912);
  ushort* Wkb   = (ushort*)(ws + 13762560);
  ushort* Wvb   = (ushort*)(ws + 14942208);
  ushort* Qb    = (ushort*)(ws + 16121856);
  ushort* Kb    = (ushort*)(ws + 28704768);
  ushort* Vtb   = (ushort*)(ws + 41287680);  // [1536][4096] bf16 transposed V
  float*  maskL = (float*)(ws + 53870592);   // mask * log2e, 8192 f32
  float*  part1 = (float*)(ws + 53903360);   // 25,165,824 B partial ctx (half 1)
  float2* lmbuf = (float2*)(ws + 79069184);  // 2 halves x 2 x 12 x 4096 float2

  cvt_kernel<<<6144, 256, 0, stream>>>(hidden, Xb, 1572864);
  cvt_kernel<<<576, 256, 0, stream>>>(Wq, Wqb, 147456);
  cvt_kernel<<<576, 256, 0, stream>>>(Wk, Wkb, 147456);
  cvt_kernel<<<576, 256, 0, stream>>>(Wv, Wvb, 147456);
  scale_kernel<<<32, 256, 0, stream>>>(mask, maskL, LOG2E, 8192);

  dim3 gg(64, 18);  // y/6 selects Q,K,V
  qkv_fused<<<gg, 256, 0, stream>>>(Xb, Wqb, Wkb, Wvb, bq, bk, bv,
                                    Qb, Kb, Vtb, 0.125f * LOG2E);

  dim3 ga(64, 12, 2);   // blockIdx.x = (qt<<1) | kv_half
  flash_attn<<<ga, 256, 0, stream>>>(Qb, Kb, Vtb, maskL,
                                     (float*)d_out, part1, lmbuf);
  merge_kernel<<<6144, 256, 0, stream>>>((float*)d_out, part1, lmbuf);
}

// Round 14
// 236.951 us; speedup vs baseline: 1.0307x; 1.0307x over previous
//
#include <hip/hip_runtime.h>
#include <hip/hip_bf16.h>

// B=2, S=4096, H=768, NH=12, HD=64
typedef float f32x4 __attribute__((ext_vector_type(4)));
typedef float f32x16 __attribute__((ext_vector_type(16)));
typedef short short8 __attribute__((ext_vector_type(8)));

#define LOG2E 1.44269504088896340736f
#define FIXED_M 24.0f   // fixed softmax shift (log2 units); exact for |sL|<~100

__device__ __forceinline__ ushort f2bf(float f){
  unsigned u = __builtin_bit_cast(unsigned, f);
  u = (u + 0x7fffu + ((u >> 16) & 1u)) >> 16;
  return (ushort)u;
}

__device__ __forceinline__ float exp2_hw(float x){
  float r; asm("v_exp_f32 %0, %1" : "=v"(r) : "v"(x)); return r;
}

// packed 2xf32 ops (VOP3P, operate on VGPR pairs)
__device__ __forceinline__ double pk_add(double a, double b){
  double d; asm("v_pk_add_f32 %0, %1, %2" : "=v"(d) : "v"(a), "v"(b)); return d;
}
__device__ __forceinline__ uint cvtpk_bf16(float lo, float hi){
  uint r; asm("v_cvt_pk_bf16_f32 %0, %1, %2" : "=v"(r) : "v"(lo), "v"(hi)); return r;
}
__device__ __forceinline__ double f2d(float x, float y){
  union { float f[2]; double d; } u; u.f[0] = x; u.f[1] = y; return u.d;
}

union F16u { f32x16 v; double d[8]; float f[16]; };

__global__ void cvt_kernel(const float* __restrict__ src, ushort* __restrict__ dst, int n4){
  int i = blockIdx.x * 256 + threadIdx.x;
  if (i < n4){
    float4 v = ((const float4*)src)[i];
    ushort4 o; o.x = f2bf(v.x); o.y = f2bf(v.y); o.z = f2bf(v.z); o.w = f2bf(v.w);
    ((ushort4*)dst)[i] = o;
  }
}

__global__ void scale_kernel(const float* __restrict__ src, float* __restrict__ dst,
                             float sc, int n){
  int i = blockIdx.x * 256 + threadIdx.x;
  if (i < n) dst[i] = src[i] * sc;
}

// Fused QKV projection: one launch, grid (64, 18). blockIdx.y/6 selects {Q,K,V}.
__global__ __launch_bounds__(256) void qkv_fused(const ushort* __restrict__ Xb,
                                                 const ushort* __restrict__ Wqb,
                                                 const ushort* __restrict__ Wkb,
                                                 const ushort* __restrict__ Wvb,
                                                 const float* __restrict__ bqp,
                                                 const float* __restrict__ bkp,
                                                 const float* __restrict__ bvp,
                                                 ushort* __restrict__ Qo,
                                                 ushort* __restrict__ Ko,
                                                 ushort* __restrict__ Vto,
                                                 float qscale){
  __shared__ ushort Xs[128*64];
  __shared__ ushort Ws[128*64];
  const int sel = blockIdx.y / 6;
  const int m0 = blockIdx.x * 128, n0 = (blockIdx.y % 6) * 128;
  const ushort* Wb  = (sel == 0) ? Wqb : (sel == 1) ? Wkb : Wvb;
  const float* bias = (sel == 0) ? bqp : (sel == 1) ? bkp : bvp;
  const int tid = threadIdx.x, w = tid >> 6, lane = tid & 63;
  const int r = lane & 15, g = lane >> 4;
  const int wr = (w >> 1) * 64, wc = (w & 1) * 64;
  const int lrow = lane >> 3;
  const int gk = (lane & 7) ^ lrow;
  f32x4 acc[4][4] = {};
  for (int k0 = 0; k0 < 768; k0 += 64){
    #pragma unroll
    for (int p = 0; p < 4; p++){
      int rowb = p*32 + w*8;
      int row = rowb + lrow;
      __builtin_amdgcn_global_load_lds(
        (const uint4*)(Xb + (size_t)(m0+row)*768 + k0 + gk*8),
        (uint4*)((char*)Xs + rowb*128), 16, 0, 0);
      __builtin_amdgcn_global_load_lds(
        (const uint4*)(Wb + (size_t)(n0+row)*768 + k0 + gk*8),
        (uint4*)((char*)Ws + rowb*128), 16, 0, 0);
    }
    __syncthreads();
    #pragma unroll
    for (int ks = 0; ks < 2; ks++){
      short8 af[4], bf[4];
      int bo = ks*64 + g*16;
      #pragma unroll
      for (int i = 0; i < 4; i++){
        int rowa = wr + i*16 + r;
        af[i] = *(const short8*)((char*)Xs + rowa*128 + (bo ^ ((rowa&7)<<4)));
        int rowb2 = wc + i*16 + r;
        bf[i] = *(const short8*)((char*)Ws + rowb2*128 + (bo ^ ((rowb2&7)<<4)));
      }
      #pragma unroll
      for (int i = 0; i < 4; i++)
        #pragma unroll
        for (int j = 0; j < 4; j++)
          acc[i][j] = __builtin_amdgcn_mfma_f32_16x16x32_bf16(af[i], bf[j], acc[i][j], 0,0,0);
    }
    __syncthreads();
  }
  if (sel < 2){
    ushort* Out = sel ? Ko : Qo;
    float scale = sel ? 1.0f : qscale;
    #pragma unroll
    for (int i = 0; i < 4; i++){
      #pragma unroll
      for (int j = 0; j < 4; j++){
        int col = n0 + wc + j*16 + r;
        float bv = bias[col];
        int rowb = m0 + wr + i*16 + g*4;
        #pragma unroll
        for (int q = 0; q < 4; q++)
          Out[(size_t)(rowb+q)*768 + col] = f2bf((acc[i][j][q] + bv) * scale);
      }
    }
  } else {
    #pragma unroll
    for (int i = 0; i < 4; i++){
      #pragma unroll
      for (int j = 0; j < 4; j++){
        int col = n0 + wc + j*16 + r;
        float bv = bias[col];
        int rowb = m0 + wr + i*16 + g*4;
        ushort4 o;
        o.x = f2bf(acc[i][j][0] + bv);
        o.y = f2bf(acc[i][j][1] + bv);
        o.z = f2bf(acc[i][j][2] + bv);
        o.w = f2bf(acc[i][j][3] + bv);
        size_t vrow = (size_t)((rowb >> 12) * 768 + col);
        *(ushort4*)(Vto + vrow * 4096 + (rowb & 4095)) = o;
      }
    }
  }
}

// Flash attention (R12 LDS/dbuf core), split-KV x2, FIXED-M softmax:
// p = exp2(sL - 24) exactly (no running max, no rescale). Partials in bf16.
__global__ __launch_bounds__(256, 3) void flash_attn(const ushort* __restrict__ Qb,
                                                     const ushort* __restrict__ Kb,
                                                     const ushort* __restrict__ Vt,
                                                     const float* __restrict__ maskL,
                                                     ushort* __restrict__ part0,
                                                     ushort* __restrict__ part1,
                                                     float* __restrict__ lsum){
  __shared__ ushort SMEM[16384];  // bytes: K0@0, K1@8192, V0@16384, V1@24576
  const int tid = threadIdx.x, w = tid >> 6, lane = tid & 63;
  const int q = lane & 31, hi = lane >> 5;
  const int swq = (q & 7) << 4;
  const int h = blockIdx.y, b = blockIdx.z;
  const int qt = blockIdx.x >> 1, half = blockIdx.x & 1;
  const int q0 = qt * 128 + w * 32;
  char* sm = (char*)SMEM;

  short8 bq[4];
  {
    const ushort* qp = Qb + (size_t)(b*4096 + q0 + q)*768 + h*64 + hi*8;
    #pragma unroll
    for (int kd = 0; kd < 4; kd++) bq[kd] = *(const short8*)(qp + 16*kd);
  }
  const ushort* Kbase = Kb + (size_t)(b*4096 + half*2048)*768 + h*64;
  const ushort* Vbase = Vt + (size_t)(b*768 + h*64)*4096 + half*2048;

  const int row0 = tid >> 3, cir = tid & 7;
  const int row1 = row0 + 32;
  const int wb0 = row0*128 + ((cir*16) ^ ((row0&7)<<4));
  const int wb1 = row1*128 + ((cir*16) ^ ((row1&7)<<4));
  const ushort* kp0 = Kbase + (size_t)row0*768 + cir*8;
  const ushort* kp1 = Kbase + (size_t)row1*768 + cir*8;
  const ushort* vp0 = Vbase + (size_t)row0*4096 + cir*8;
  const ushort* vp1 = Vbase + (size_t)row1*4096 + cir*8;

  int off4[4];
  #pragma unroll
  for (int kd = 0; kd < 4; kd++)
    off4[kd] = q*128 + ((32*kd + 16*hi) ^ swq);

  // tile0 -> buf0, tile1 -> regs
  uint4 k0r = *(const uint4*)kp0, k1r = *(const uint4*)kp1;
  uint4 v0r = *(const uint4*)vp0, v1r = *(const uint4*)vp1;
  *(uint4*)(sm + wb0) = k0r;           *(uint4*)(sm + wb1) = k1r;
  *(uint4*)(sm + 16384 + wb0) = v0r;   *(uint4*)(sm + 16384 + wb1) = v1r;
  k0r = *(const uint4*)(kp0 + (size_t)64*768);
  k1r = *(const uint4*)(kp1 + (size_t)64*768);
  v0r = *(const uint4*)(vp0 + 64);
  v1r = *(const uint4*)(vp1 + 64);
  __syncthreads();

  F16u c0, c1;
  { f32x16 zz = {}; c0.v = zz; c1.v = zz; }
  float lrun = 0.f;
  const double msub = f2d(-FIXED_M, -FIXED_M);

  for (int t = 0; t < 32; t++){
    const int tb = (t & 1) << 13;
    const char* kb = sm + tb;
    const char* vb = kb + 16384;
    // QK^T
    __builtin_amdgcn_s_setprio(1);
    f32x16 z0 = {}, z1 = {};
    #pragma unroll
    for (int kd = 0; kd < 4; kd++){
      short8 ak = *(const short8*)(kb + off4[kd]);
      z0 = __builtin_amdgcn_mfma_f32_32x32x16_bf16(ak, bq[kd], z0, 0,0,0);
    }
    #pragma unroll
    for (int kd = 0; kd < 4; kd++){
      short8 ak = *(const short8*)(kb + 4096 + off4[kd]);
      z1 = __builtin_amdgcn_mfma_f32_32x32x16_bf16(ak, bq[kd], z1, 0,0,0);
    }
    __builtin_amdgcn_s_setprio(0);
    F16u s0, s1; s0.v = z0; s1.v = z1;
    // stage t+1 regs -> other buffer
    if (t < 31){
      char* wbuf = sm + (tb ^ 8192);
      *(uint4*)(wbuf + wb0) = k0r;           *(uint4*)(wbuf + wb1) = k1r;
      *(uint4*)(wbuf + 16384 + wb0) = v0r;   *(uint4*)(wbuf + 16384 + wb1) = v1r;
    }
    // issue loads for t+2
    if (t < 30){
      const size_t kn = (size_t)(t+2) * 64;
      k0r = *(const uint4*)(kp0 + kn*768);
      k1r = *(const uint4*)(kp1 + kn*768);
      v0r = *(const uint4*)(vp0 + kn);
      v1r = *(const uint4*)(vp1 + kn);
    }
    // + mask (log2-scaled) and -M, packed adds; then per-element exp2
    const float* mrow = maskL + b*4096 + half*2048 + t*64 + hi*4;
    #pragma unroll
    for (int eq = 0; eq < 4; eq++){
      float4 m0v = *(const float4*)(mrow + eq*8);
      s0.d[2*eq]   = pk_add(s0.d[2*eq],   f2d(m0v.x, m0v.y));
      s0.d[2*eq+1] = pk_add(s0.d[2*eq+1], f2d(m0v.z, m0v.w));
      float4 m1v = *(const float4*)(mrow + 32 + eq*8);
      s1.d[2*eq]   = pk_add(s1.d[2*eq],   f2d(m1v.x, m1v.y));
      s1.d[2*eq+1] = pk_add(s1.d[2*eq+1], f2d(m1v.z, m1v.w));
    }
    #pragma unroll
    for (int i = 0; i < 8; i++){
      s0.d[i] = pk_add(s0.d[i], msub);
      s1.d[i] = pk_add(s1.d[i], msub);
    }
    #pragma unroll
    for (int e = 0; e < 16; e++){
      s0.f[e] = exp2_hw(s0.f[e]);
      s1.f[e] = exp2_hw(s1.f[e]);
    }
    // row-sum via packed tree
    double t00 = pk_add(s0.d[0], s0.d[1]), t01 = pk_add(s0.d[2], s0.d[3]);
    double t02 = pk_add(s0.d[4], s0.d[5]), t03 = pk_add(s0.d[6], s0.d[7]);
    double t10 = pk_add(s1.d[0], s1.d[1]), t11 = pk_add(s1.d[2], s1.d[3]);
    double t12 = pk_add(s1.d[4], s1.d[5]), t13 = pk_add(s1.d[6], s1.d[7]);
    double u0 = pk_add(t00, t01), u1 = pk_add(t02, t03);
    double u2 = pk_add(t10, t11), u3 = pk_add(t12, t13);
    double wsum = pk_add(pk_add(u0, u1), pk_add(u2, u3));
    {
      union { double d; float f[2]; } uw; uw.d = wsum;
      float rs = uw.f[0] + uw.f[1];
      rs += __shfl_xor(rs, 32, 64);
      lrun += rs;
    }
    // pack P (cvt_pk) + permlane32_swap -> PV B-frags
    short8 bp[4];
    {
      uint pw[8];
      #pragma unroll
      for (int u = 0; u < 8; u++) pw[u] = cvtpk_bf16(s0.f[2*u], s0.f[2*u+1]);
      #pragma unroll
      for (int u2 = 0; u2 < 2; u2++){
        uint x0 = pw[4*u2+0], x1 = pw[4*u2+1], x2 = pw[4*u2+2], x3 = pw[4*u2+3];
        asm("v_permlane32_swap_b32 %0, %1" : "+v"(x0), "+v"(x2));
        asm("v_permlane32_swap_b32 %0, %1" : "+v"(x1), "+v"(x3));
        union { uint u[4]; short8 v; } bb;
        bb.u[0] = x0; bb.u[1] = x1; bb.u[2] = x2; bb.u[3] = x3;
        bp[u2] = bb.v;
      }
      #pragma unroll
      for (int u = 0; u < 8; u++) pw[u] = cvtpk_bf16(s1.f[2*u], s1.f[2*u+1]);
      #pragma unroll
      for (int u2 = 0; u2 < 2; u2++){
        uint x0 = pw[4*u2+0], x1 = pw[4*u2+1], x2 = pw[4*u2+2], x3 = pw[4*u2+3];
        asm("v_permlane32_swap_b32 %0, %1" : "+v"(x0), "+v"(x2));
        asm("v_permlane32_swap_b32 %0, %1" : "+v"(x1), "+v"(x3));
        union { uint u[4]; short8 v; } bb;
        bb.u[0] = x0; bb.u[1] = x1; bb.u[2] = x2; bb.u[3] = x3;
        bp[2+u2] = bb.v;
      }
    }
    // PV
    __builtin_amdgcn_s_setprio(1);
    #pragma unroll
    for (int kk = 0; kk < 4; kk++){
      short8 av = *(const short8*)(vb + off4[kk]);
      c0.v = __builtin_amdgcn_mfma_f32_32x32x16_bf16(av, bp[kk], c0.v, 0,0,0);
    }
    #pragma unroll
    for (int kk = 0; kk < 4; kk++){
      short8 av = *(const short8*)(vb + 4096 + off4[kk]);
      c1.v = __builtin_amdgcn_mfma_f32_32x32x16_bf16(av, bp[kk], c1.v, 0,0,0);
    }
    __builtin_amdgcn_s_setprio(0);
    __syncthreads();
  }
  // epilogue: write UNNORMALIZED bf16 partial ctx + l
  ushort* part = half ? part1 : part0;
  size_t orow = (size_t)(b*4096 + q0 + q) * 768 + h*64;
  #pragma unroll
  for (int eq = 0; eq < 4; eq++){
    uint2 o;
    o.x = cvtpk_bf16(c0.f[4*eq+0], c0.f[4*eq+1]);
    o.y = cvtpk_bf16(c0.f[4*eq+2], c0.f[4*eq+3]);
    *(uint2*)(part + orow + eq*8 + hi*4) = o;
  }
  #pragma unroll
  for (int eq = 0; eq < 4; eq++){
    uint2 o;
    o.x = cvtpk_bf16(c1.f[4*eq+0], c1.f[4*eq+1]);
    o.y = cvtpk_bf16(c1.f[4*eq+2], c1.f[4*eq+3]);
    *(uint2*)(part + orow + 32 + eq*8 + hi*4) = o;
  }
  if (hi == 0){
    int idx = ((half*2 + b)*12 + h)*4096 + (q0 + q);
    lsum[idx] = lrun;
  }
}

// O = (c0 + c1) / (l0 + l1); partials bf16, fixed-M on both halves.
__global__ void merge_kernel(const ushort* __restrict__ p0, const ushort* __restrict__ p1,
                             const float* __restrict__ lsum, float* __restrict__ out){
  int i = blockIdx.x * 256 + threadIdx.x;     // float4 index
  const int nf4 = 2*4096*768/4;
  if (i >= nf4) return;
  int f = i * 4;
  int b = f / (4096*768);
  int rem = f - b*(4096*768);
  int qrow = rem / 768;
  int col = rem - qrow*768;
  int head = col >> 6;
  float l0 = lsum[((    b)*12 + head)*4096 + qrow];
  float l1 = lsum[((2 + b)*12 + head)*4096 + qrow];
  float inv = 1.0f / (l0 + l1);
  uint2 a = ((const uint2*)p0)[i];
  uint2 c = ((const uint2*)p1)[i];
  float4 o;
  o.x = (__builtin_bit_cast(float, a.x << 16)          + __builtin_bit_cast(float, c.x << 16))          * inv;
  o.y = (__builtin_bit_cast(float, a.x & 0xffff0000u)  + __builtin_bit_cast(float, c.x & 0xffff0000u))  * inv;
  o.z = (__builtin_bit_cast(float, a.y << 16)          + __builtin_bit_cast(float, c.y << 16))          * inv;
  o.w = (__builtin_bit_cast(float, a.y & 0xffff0000u)  + __builtin_bit_cast(float, c.y & 0xffff0000u))  * inv;
  ((float4*)out)[i] = o;
}

extern "C" void kernel_launch(void* const* d_in, const int* in_sizes, int n_in,
                              void* d_out, int out_size, void* d_ws, size_t ws_size,
                              hipStream_t stream){
  const float* hidden = (const float*)d_in[0];
  const float* mask   = (const float*)d_in[1];
  const float* Wq     = (const float*)d_in[2];
  const float* bq     = (const float*)d_in[3];
  const float* Wk     = (const float*)d_in[4];
  const float* bk     = (const float*)d_in[5];
  const float* Wv     = (const float*)d_in[6];
  const float* bv     = (const float*)d_in[7];
  char* ws = (char*)d_ws;
  ushort* Xb    = (ushort*)(ws);
  ushort* Wqb   = (ushort*)(ws + 12582912);
  ushort* Wkb   = (ushort*)(ws + 13762560);
  ushort* Wvb   = (ushort*)(ws + 14942208);
  ushort* Qb    = (ushort*)(ws + 16121856);
  ushort* Kb    = (ushort*)(ws + 28704768);
  ushort* Vtb   = (ushort*)(ws + 41287680);  // [1536][4096] bf16 transposed V
  float*  maskL = (float*)(ws + 53870592);   // mask * log2e, 8192 f32
  ushort* part0 = (ushort*)(ws + 53903360);  // bf16 partial ctx (half 0), 12.58 MB
  ushort* part1 = (ushort*)(ws + 66486272);  // bf16 partial ctx (half 1), 12.58 MB
  float*  lbuf  = (float*)(ws + 79069184);   // 2 halves x 2 x 12 x 4096 f32

  cvt_kernel<<<6144, 256, 0, stream>>>(hidden, Xb, 1572864);
  cvt_kernel<<<576, 256, 0, stream>>>(Wq, Wqb, 147456);
  cvt_kernel<<<576, 256, 0, stream>>>(Wk, Wkb, 147456);
  cvt_kernel<<<576, 256, 0, stream>>>(Wv, Wvb, 147456);
  scale_kernel<<<32, 256, 0, stream>>>(mask, maskL, LOG2E, 8192);

  dim3 gg(64, 18);  // y/6 selects Q,K,V
  qkv_fused<<<gg, 256, 0, stream>>>(Xb, Wqb, Wkb, Wvb, bq, bk, bv,
                                    Qb, Kb, Vtb, 0.125f * LOG2E);

  dim3 ga(64, 12, 2);   // blockIdx.x = (qt<<1) | kv_half
  flash_attn<<<ga, 256, 0, stream>>>(Qb, Kb, Vtb, maskL, part0, part1, lbuf);
  merge_kernel<<<6144, 256, 0, stream>>>(part0, part1, lbuf, (float*)d_out);
}

// Round 15
// 225.026 us; speedup vs baseline: 1.0854x; 1.0530x over previous
//
#include <hip/hip_runtime.h>
#include <hip/hip_bf16.h>

// B=2, S=4096, H=768, NH=12, HD=64
typedef float f32x4 __attribute__((ext_vector_type(4)));
typedef float f32x16 __attribute__((ext_vector_type(16)));
typedef short short8 __attribute__((ext_vector_type(8)));

#define LOG2E 1.44269504088896340736f

__device__ __forceinline__ ushort f2bf(float f){
  unsigned u = __builtin_bit_cast(unsigned, f);
  u = (u + 0x7fffu + ((u >> 16) & 1u)) >> 16;
  return (ushort)u;
}

__device__ __forceinline__ float exp2_hw(float x){
  float r; asm("v_exp_f32 %0, %1" : "=v"(r) : "v"(x)); return r;
}

// packed 2xf32 ops (VOP3P, operate on VGPR pairs)
__device__ __forceinline__ double pk_add(double a, double b){
  double d; asm("v_pk_add_f32 %0, %1, %2" : "=v"(d) : "v"(a), "v"(b)); return d;
}
__device__ __forceinline__ double pk_mul(double a, double b){
  double d; asm("v_pk_mul_f32 %0, %1, %2" : "=v"(d) : "v"(a), "v"(b)); return d;
}
__device__ __forceinline__ uint cvtpk_bf16(float lo, float hi){
  uint r; asm("v_cvt_pk_bf16_f32 %0, %1, %2" : "=v"(r) : "v"(lo), "v"(hi)); return r;
}
__device__ __forceinline__ double f2d(float x, float y){
  union { float f[2]; double d; } u; u.f[0] = x; u.f[1] = y; return u.d;
}
__device__ __forceinline__ float fmax3(float a, float b, float c){
  return fmaxf(fmaxf(a, b), c);   // clang fuses to v_max3_f32
}

union F16u { f32x16 v; double d[8]; float f[16]; };

__global__ void cvt_kernel(const float* __restrict__ src, ushort* __restrict__ dst, int n4){
  int i = blockIdx.x * 256 + threadIdx.x;
  if (i < n4){
    float4 v = ((const float4*)src)[i];
    ushort4 o; o.x = f2bf(v.x); o.y = f2bf(v.y); o.z = f2bf(v.z); o.w = f2bf(v.w);
    ((ushort4*)dst)[i] = o;
  }
}

__global__ void scale_kernel(const float* __restrict__ src, float* __restrict__ dst,
                             float sc, int n){
  int i = blockIdx.x * 256 + threadIdx.x;
  if (i < n) dst[i] = src[i] * sc;
}

// Fused QKV projection: one launch, grid (64, 18). blockIdx.y/6 selects {Q,K,V}.
__global__ __launch_bounds__(256) void qkv_fused(const ushort* __restrict__ Xb,
                                                 const ushort* __restrict__ Wqb,
                                                 const ushort* __restrict__ Wkb,
                                                 const ushort* __restrict__ Wvb,
                                                 const float* __restrict__ bqp,
                                                 const float* __restrict__ bkp,
                                                 const float* __restrict__ bvp,
                                                 ushort* __restrict__ Qo,
                                                 ushort* __restrict__ Ko,
                                                 ushort* __restrict__ Vto,
                                                 float qscale){
  __shared__ ushort Xs[128*64];
  __shared__ ushort Ws[128*64];
  const int sel = blockIdx.y / 6;
  const int m0 = blockIdx.x * 128, n0 = (blockIdx.y % 6) * 128;
  const ushort* Wb  = (sel == 0) ? Wqb : (sel == 1) ? Wkb : Wvb;
  const float* bias = (sel == 0) ? bqp : (sel == 1) ? bkp : bvp;
  const int tid = threadIdx.x, w = tid >> 6, lane = tid & 63;
  const int r = lane & 15, g = lane >> 4;
  const int wr = (w >> 1) * 64, wc = (w & 1) * 64;
  const int lrow = lane >> 3;
  const int gk = (lane & 7) ^ lrow;
  f32x4 acc[4][4] = {};
  for (int k0 = 0; k0 < 768; k0 += 64){
    #pragma unroll
    for (int p = 0; p < 4; p++){
      int rowb = p*32 + w*8;
      int row = rowb + lrow;
      __builtin_amdgcn_global_load_lds(
        (const uint4*)(Xb + (size_t)(m0+row)*768 + k0 + gk*8),
        (uint4*)((char*)Xs + rowb*128), 16, 0, 0);
      __builtin_amdgcn_global_load_lds(
        (const uint4*)(Wb + (size_t)(n0+row)*768 + k0 + gk*8),
        (uint4*)((char*)Ws + rowb*128), 16, 0, 0);
    }
    __syncthreads();
    #pragma unroll
    for (int ks = 0; ks < 2; ks++){
      short8 af[4], bf[4];
      int bo = ks*64 + g*16;
      #pragma unroll
      for (int i = 0; i < 4; i++){
        int rowa = wr + i*16 + r;
        af[i] = *(const short8*)((char*)Xs + rowa*128 + (bo ^ ((rowa&7)<<4)));
        int rowb2 = wc + i*16 + r;
        bf[i] = *(const short8*)((char*)Ws + rowb2*128 + (bo ^ ((rowb2&7)<<4)));
      }
      #pragma unroll
      for (int i = 0; i < 4; i++)
        #pragma unroll
        for (int j = 0; j < 4; j++)
          acc[i][j] = __builtin_amdgcn_mfma_f32_16x16x32_bf16(af[i], bf[j], acc[i][j], 0,0,0);
    }
    __syncthreads();
  }
  if (sel < 2){
    ushort* Out = sel ? Ko : Qo;
    float scale = sel ? 1.0f : qscale;
    #pragma unroll
    for (int i = 0; i < 4; i++){
      #pragma unroll
      for (int j = 0; j < 4; j++){
        int col = n0 + wc + j*16 + r;
        float bv = bias[col];
        int rowb = m0 + wr + i*16 + g*4;
        #pragma unroll
        for (int q = 0; q < 4; q++)
          Out[(size_t)(rowb+q)*768 + col] = f2bf((acc[i][j][q] + bv) * scale);
      }
    }
  } else {
    #pragma unroll
    for (int i = 0; i < 4; i++){
      #pragma unroll
      for (int j = 0; j < 4; j++){
        int col = n0 + wc + j*16 + r;
        float bv = bias[col];
        int rowb = m0 + wr + i*16 + g*4;
        ushort4 o;
        o.x = f2bf(acc[i][j][0] + bv);
        o.y = f2bf(acc[i][j][1] + bv);
        o.z = f2bf(acc[i][j][2] + bv);
        o.w = f2bf(acc[i][j][3] + bv);
        size_t vrow = (size_t)((rowb >> 12) * 768 + col);
        *(ushort4*)(Vto + vrow * 4096 + (rowb & 4095)) = o;
      }
    }
  }
}

// Flash attention: R12 compute core EXACTLY (online max + defer-max, dbuf LDS,
// split-KV x2). Only the epilogue differs: partials stored as bf16 + (m,l).
__global__ __launch_bounds__(256, 3) void flash_attn(const ushort* __restrict__ Qb,
                                                     const ushort* __restrict__ Kb,
                                                     const ushort* __restrict__ Vt,
                                                     const float* __restrict__ maskL,
                                                     ushort* __restrict__ part0,
                                                     ushort* __restrict__ part1,
                                                     float2* __restrict__ lm){
  __shared__ ushort SMEM[16384];  // bytes: K0@0, K1@8192, V0@16384, V1@24576
  const int tid = threadIdx.x, w = tid >> 6, lane = tid & 63;
  const int q = lane & 31, hi = lane >> 5;
  const int swq = (q & 7) << 4;
  const int h = blockIdx.y, b = blockIdx.z;
  const int qt = blockIdx.x >> 1, half = blockIdx.x & 1;
  const int q0 = qt * 128 + w * 32;
  char* sm = (char*)SMEM;

  short8 bq[4];
  {
    const ushort* qp = Qb + (size_t)(b*4096 + q0 + q)*768 + h*64 + hi*8;
    #pragma unroll
    for (int kd = 0; kd < 4; kd++) bq[kd] = *(const short8*)(qp + 16*kd);
  }
  const ushort* Kbase = Kb + (size_t)(b*4096 + half*2048)*768 + h*64;
  const ushort* Vbase = Vt + (size_t)(b*768 + h*64)*4096 + half*2048;

  const int row0 = tid >> 3, cir = tid & 7;
  const int row1 = row0 + 32;
  const int wb0 = row0*128 + ((cir*16) ^ ((row0&7)<<4));
  const int wb1 = row1*128 + ((cir*16) ^ ((row1&7)<<4));
  const ushort* kp0 = Kbase + (size_t)row0*768 + cir*8;
  const ushort* kp1 = Kbase + (size_t)row1*768 + cir*8;
  const ushort* vp0 = Vbase + (size_t)row0*4096 + cir*8;
  const ushort* vp1 = Vbase + (size_t)row1*4096 + cir*8;

  int off4[4];
  #pragma unroll
  for (int kd = 0; kd < 4; kd++)
    off4[kd] = q*128 + ((32*kd + 16*hi) ^ swq);

  // tile0 -> buf0, tile1 -> regs
  uint4 k0r = *(const uint4*)kp0, k1r = *(const uint4*)kp1;
  uint4 v0r = *(const uint4*)vp0, v1r = *(const uint4*)vp1;
  *(uint4*)(sm + wb0) = k0r;           *(uint4*)(sm + wb1) = k1r;
  *(uint4*)(sm + 16384 + wb0) = v0r;   *(uint4*)(sm + 16384 + wb1) = v1r;
  k0r = *(const uint4*)(kp0 + (size_t)64*768);
  k1r = *(const uint4*)(kp1 + (size_t)64*768);
  v0r = *(const uint4*)(vp0 + 64);
  v1r = *(const uint4*)(vp1 + 64);
  __syncthreads();

  F16u c0, c1;
  { f32x16 zz = {}; c0.v = zz; c1.v = zz; }
  float mrun = -1e30f, lrun = 0.f;

  for (int t = 0; t < 32; t++){
    const int tb = (t & 1) << 13;
    const char* kb = sm + tb;
    const char* vb = kb + 16384;
    // QK^T
    __builtin_amdgcn_s_setprio(1);
    f32x16 z0 = {}, z1 = {};
    #pragma unroll
    for (int kd = 0; kd < 4; kd++){
      short8 ak = *(const short8*)(kb + off4[kd]);
      z0 = __builtin_amdgcn_mfma_f32_32x32x16_bf16(ak, bq[kd], z0, 0,0,0);
    }
    #pragma unroll
    for (int kd = 0; kd < 4; kd++){
      short8 ak = *(const short8*)(kb + 4096 + off4[kd]);
      z1 = __builtin_amdgcn_mfma_f32_32x32x16_bf16(ak, bq[kd], z1, 0,0,0);
    }
    __builtin_amdgcn_s_setprio(0);
    F16u s0, s1; s0.v = z0; s1.v = z1;
    // stage t+1 regs -> other buffer
    if (t < 31){
      char* wbuf = sm + (tb ^ 8192);
      *(uint4*)(wbuf + wb0) = k0r;           *(uint4*)(wbuf + wb1) = k1r;
      *(uint4*)(wbuf + 16384 + wb0) = v0r;   *(uint4*)(wbuf + 16384 + wb1) = v1r;
    }
    // issue loads for t+2
    if (t < 30){
      const size_t kn = (size_t)(t+2) * 64;
      k0r = *(const uint4*)(kp0 + kn*768);
      k1r = *(const uint4*)(kp1 + kn*768);
      v0r = *(const uint4*)(vp0 + kn);
      v1r = *(const uint4*)(vp1 + kn);
    }
    // + mask (log2-scaled), packed adds
    const float* mrow = maskL + b*4096 + half*2048 + t*64 + hi*4;
    #pragma unroll
    for (int eq = 0; eq < 4; eq++){
      float4 m0v = *(const float4*)(mrow + eq*8);
      s0.d[2*eq]   = pk_add(s0.d[2*eq],   f2d(m0v.x, m0v.y));
      s0.d[2*eq+1] = pk_add(s0.d[2*eq+1], f2d(m0v.z, m0v.w));
      float4 m1v = *(const float4*)(mrow + 32 + eq*8);
      s1.d[2*eq]   = pk_add(s1.d[2*eq],   f2d(m1v.x, m1v.y));
      s1.d[2*eq+1] = pk_add(s1.d[2*eq+1], f2d(m1v.z, m1v.w));
    }
    // max over 32 in-lane values + lane^32 exchange
    float ma = fmax3(s0.f[0], s0.f[1], s0.f[2]);
    float mb = fmax3(s0.f[3], s0.f[4], s0.f[5]);
    ma = fmax3(ma, s0.f[6], s0.f[7]);
    mb = fmax3(mb, s0.f[8], s0.f[9]);
    ma = fmax3(ma, s0.f[10], s0.f[11]);
    mb = fmax3(mb, s0.f[12], s0.f[13]);
    ma = fmax3(ma, s0.f[14], s0.f[15]);
    mb = fmax3(mb, s1.f[0], s1.f[1]);
    ma = fmax3(ma, s1.f[2], s1.f[3]);
    mb = fmax3(mb, s1.f[4], s1.f[5]);
    ma = fmax3(ma, s1.f[6], s1.f[7]);
    mb = fmax3(mb, s1.f[8], s1.f[9]);
    ma = fmax3(ma, s1.f[10], s1.f[11]);
    mb = fmax3(mb, s1.f[12], s1.f[13]);
    float mt = fmax3(ma, s1.f[14], fmaxf(mb, s1.f[15]));
    mt = fmaxf(mt, __shfl_xor(mt, 32, 64));
    // defer-max (THR = 8*log2e)
    if (!__all(mt <= mrun + 11.5415603f)){
      float mnew = fmaxf(mrun, mt);
      float alpha = exp2_hw(mrun - mnew);
      mrun = mnew;
      lrun *= alpha;
      double al2 = f2d(alpha, alpha);
      #pragma unroll
      for (int i = 0; i < 8; i++){
        c0.d[i] = pk_mul(c0.d[i], al2);
        c1.d[i] = pk_mul(c1.d[i], al2);
      }
    }
    // p = exp2(s - mrun)
    double msub = f2d(-mrun, -mrun);
    #pragma unroll
    for (int i = 0; i < 8; i++){
      s0.d[i] = pk_add(s0.d[i], msub);
      s1.d[i] = pk_add(s1.d[i], msub);
    }
    #pragma unroll
    for (int e = 0; e < 16; e++){
      s0.f[e] = exp2_hw(s0.f[e]);
      s1.f[e] = exp2_hw(s1.f[e]);
    }
    // row-sum via packed tree
    double t00 = pk_add(s0.d[0], s0.d[1]), t01 = pk_add(s0.d[2], s0.d[3]);
    double t02 = pk_add(s0.d[4], s0.d[5]), t03 = pk_add(s0.d[6], s0.d[7]);
    double t10 = pk_add(s1.d[0], s1.d[1]), t11 = pk_add(s1.d[2], s1.d[3]);
    double t12 = pk_add(s1.d[4], s1.d[5]), t13 = pk_add(s1.d[6], s1.d[7]);
    double u0 = pk_add(t00, t01), u1 = pk_add(t02, t03);
    double u2 = pk_add(t10, t11), u3 = pk_add(t12, t13);
    double wsum = pk_add(pk_add(u0, u1), pk_add(u2, u3));
    {
      union { double d; float f[2]; } uw; uw.d = wsum;
      float rs = uw.f[0] + uw.f[1];
      rs += __shfl_xor(rs, 32, 64);
      lrun += rs;
    }
    // pack P (cvt_pk) + permlane32_swap -> PV B-frags
    short8 bp[4];
    {
      uint pw[8];
      #pragma unroll
      for (int u = 0; u < 8; u++) pw[u] = cvtpk_bf16(s0.f[2*u], s0.f[2*u+1]);
      #pragma unroll
      for (int u2 = 0; u2 < 2; u2++){
        uint x0 = pw[4*u2+0], x1 = pw[4*u2+1], x2 = pw[4*u2+2], x3 = pw[4*u2+3];
        asm("v_permlane32_swap_b32 %0, %1" : "+v"(x0), "+v"(x2));
        asm("v_permlane32_swap_b32 %0, %1" : "+v"(x1), "+v"(x3));
        union { uint u[4]; short8 v; } bb;
        bb.u[0] = x0; bb.u[1] = x1; bb.u[2] = x2; bb.u[3] = x3;
        bp[u2] = bb.v;
      }
      #pragma unroll
      for (int u = 0; u < 8; u++) pw[u] = cvtpk_bf16(s1.f[2*u], s1.f[2*u+1]);
      #pragma unroll
      for (int u2 = 0; u2 < 2; u2++){
        uint x0 = pw[4*u2+0], x1 = pw[4*u2+1], x2 = pw[4*u2+2], x3 = pw[4*u2+3];
        asm("v_permlane32_swap_b32 %0, %1" : "+v"(x0), "+v"(x2));
        asm("v_permlane32_swap_b32 %0, %1" : "+v"(x1), "+v"(x3));
        union { uint u[4]; short8 v; } bb;
        bb.u[0] = x0; bb.u[1] = x1; bb.u[2] = x2; bb.u[3] = x3;
        bp[2+u2] = bb.v;
      }
    }
    // PV
    __builtin_amdgcn_s_setprio(1);
    #pragma unroll
    for (int kk = 0; kk < 4; kk++){
      short8 av = *(const short8*)(vb + off4[kk]);
      c0.v = __builtin_amdgcn_mfma_f32_32x32x16_bf16(av, bp[kk], c0.v, 0,0,0);
    }
    #pragma unroll
    for (int kk = 0; kk < 4; kk++){
      short8 av = *(const short8*)(vb + 4096 + off4[kk]);
      c1.v = __builtin_amdgcn_mfma_f32_32x32x16_bf16(av, bp[kk], c1.v, 0,0,0);
    }
    __builtin_amdgcn_s_setprio(0);
    __syncthreads();
  }
  // epilogue: write UNNORMALIZED bf16 partial ctx + (m,l)
  ushort* part = half ? part1 : part0;
  size_t orow = (size_t)(b*4096 + q0 + q) * 768 + h*64;
  #pragma unroll
  for (int eq = 0; eq < 4; eq++){
    uint2 o;
    o.x = cvtpk_bf16(c0.f[4*eq+0], c0.f[4*eq+1]);
    o.y = cvtpk_bf16(c0.f[4*eq+2], c0.f[4*eq+3]);
    *(uint2*)(part + orow + eq*8 + hi*4) = o;
  }
  #pragma unroll
  for (int eq = 0; eq < 4; eq++){
    uint2 o;
    o.x = cvtpk_bf16(c1.f[4*eq+0], c1.f[4*eq+1]);
    o.y = cvtpk_bf16(c1.f[4*eq+2], c1.f[4*eq+3]);
    *(uint2*)(part + orow + 32 + eq*8 + hi*4) = o;
  }
  if (hi == 0){
    int idx = ((half*2 + b)*12 + h)*4096 + (q0 + q);
    lm[idx] = make_float2(mrun, lrun);
  }
}

// O = (c0*e0 + c1*e1) / (l0*e0 + l1*e1); partials bf16, e_i = exp2(m_i - max).
__global__ void merge_kernel(const ushort* __restrict__ p0, const ushort* __restrict__ p1,
                             const float2* __restrict__ lm, float* __restrict__ out){
  int i = blockIdx.x * 256 + threadIdx.x;     // float4 index
  const int nf4 = 2*4096*768/4;
  if (i >= nf4) return;
  int f = i * 4;
  int b = f / (4096*768);
  int rem = f - b*(4096*768);
  int qrow = rem / 768;
  int col = rem - qrow*768;
  int head = col >> 6;
  float2 L0 = lm[((    b)*12 + head)*4096 + qrow];
  float2 L1 = lm[((2 + b)*12 + head)*4096 + qrow];
  float M = fmaxf(L0.x, L1.x);
  float e0 = exp2f(L0.x - M), e1 = exp2f(L1.x - M);
  float inv = 1.0f / (L0.y*e0 + L1.y*e1);
  float s0 = e0 * inv, s1 = e1 * inv;
  uint2 a = ((const uint2*)p0)[i];
  uint2 c = ((const uint2*)p1)[i];
  float4 o;
  o.x = __builtin_bit_cast(float, a.x << 16)         * s0 + __builtin_bit_cast(float, c.x << 16)         * s1;
  o.y = __builtin_bit_cast(float, a.x & 0xffff0000u) * s0 + __builtin_bit_cast(float, c.x & 0xffff0000u) * s1;
  o.z = __builtin_bit_cast(float, a.y << 16)         * s0 + __builtin_bit_cast(float, c.y << 16)         * s1;
  o.w = __builtin_bit_cast(float, a.y & 0xffff0000u) * s0 + __builtin_bit_cast(float, c.y & 0xffff0000u) * s1;
  ((float4*)out)[i] = o;
}

extern "C" void kernel_launch(void* const* d_in, const int* in_sizes, int n_in,
                              void* d_out, int out_size, void* d_ws, size_t ws_size,
                              hipStream_t stream){
  const float* hidden = (const float*)d_in[0];
  const float* mask   = (const float*)d_in[1];
  const float* Wq     = (const float*)d_in[2];
  const float* bq     = (const float*)d_in[3];
  const float* Wk     = (const float*)d_in[4];
  const float* bk     = (const float*)d_in[5];
  const float* Wv     = (const float*)d_in[6];
  const float* bv     = (const float*)d_in[7];
  char* ws = (char*)d_ws;
  ushort* Xb    = (ushort*)(ws);
  ushort* Wqb   = (ushort*)(ws + 12582912);
  ushort* Wkb   = (ushort*)(ws + 13762560);
  ushort* Wvb   = (ushort*)(ws + 14942208);
  ushort* Qb    = (ushort*)(ws + 16121856);
  ushort* Kb    = (ushort*)(ws + 28704768);
  ushort* Vtb   = (ushort*)(ws + 41287680);  // [1536][4096] bf16 transposed V
  float*  maskL = (float*)(ws + 53870592);   // mask * log2e, 8192 f32
  ushort* part0 = (ushort*)(ws + 53903360);  // bf16 partial ctx (half 0), 12.58 MB
  ushort* part1 = (ushort*)(ws + 66486272);  // bf16 partial ctx (half 1), 12.58 MB
  float2* lmbuf = (float2*)(ws + 79069184);  // 2 halves x 2 x 12 x 4096 float2

  cvt_kernel<<<6144, 256, 0, stream>>>(hidden, Xb, 1572864);
  cvt_kernel<<<576, 256, 0, stream>>>(Wq, Wqb, 147456);
  cvt_kernel<<<576, 256, 0, stream>>>(Wk, Wkb, 147456);
  cvt_kernel<<<576, 256, 0, stream>>>(Wv, Wvb, 147456);
  scale_kernel<<<32, 256, 0, stream>>>(mask, maskL, LOG2E, 8192);

  dim3 gg(64, 18);  // y/6 selects Q,K,V
  qkv_fused<<<gg, 256, 0, stream>>>(Xb, Wqb, Wkb, Wvb, bq, bk, bv,
                                    Qb, Kb, Vtb, 0.125f * LOG2E);

  dim3 ga(64, 12, 2);   // blockIdx.x = (qt<<1) | kv_half
  flash_attn<<<ga, 256, 0, stream>>>(Qb, Kb, Vtb, maskL, part0, part1, lmbuf);
  merge_kernel<<<6144, 256, 0, stream>>>(part0, part1, lmbuf, (float*)d_out);
}

// Round 16
// 219.173 us; speedup vs baseline: 1.1144x; 1.0267x over previous
//
#include <hip/hip_runtime.h>
#include <hip/hip_bf16.h>

// B=2, S=4096, H=768, NH=12, HD=64
typedef float f32x4 __attribute__((ext_vector_type(4)));
typedef float f32x16 __attribute__((ext_vector_type(16)));
typedef short short8 __attribute__((ext_vector_type(8)));

#define LOG2E 1.44269504088896340736f

__device__ __forceinline__ ushort f2bf(float f){
  unsigned u = __builtin_bit_cast(unsigned, f);
  u = (u + 0x7fffu + ((u >> 16) & 1u)) >> 16;
  return (ushort)u;
}

__device__ __forceinline__ float exp2_hw(float x){
  float r; asm("v_exp_f32 %0, %1" : "=v"(r) : "v"(x)); return r;
}

// packed 2xf32 ops (VOP3P, operate on VGPR pairs)
__device__ __forceinline__ double pk_add(double a, double b){
  double d; asm("v_pk_add_f32 %0, %1, %2" : "=v"(d) : "v"(a), "v"(b)); return d;
}
__device__ __forceinline__ double pk_mul(double a, double b){
  double d; asm("v_pk_mul_f32 %0, %1, %2" : "=v"(d) : "v"(a), "v"(b)); return d;
}
__device__ __forceinline__ uint cvtpk_bf16(float lo, float hi){
  uint r; asm("v_cvt_pk_bf16_f32 %0, %1, %2" : "=v"(r) : "v"(lo), "v"(hi)); return r;
}
__device__ __forceinline__ double f2d(float x, float y){
  union { float f[2]; double d; } u; u.f[0] = x; u.f[1] = y; return u.d;
}
__device__ __forceinline__ float fmax3(float a, float b, float c){
  return fmaxf(fmaxf(a, b), c);   // clang fuses to v_max3_f32
}

union F16u { f32x16 v; double d[8]; float f[16]; };

// Fused prologue elementwise pass: ONE launch for
//   hidden f32->bf16 (6144 blocks), Wq/Wk/Wv f32->bf16 (576 each),
//   mask * log2e (8 blocks).  All segments are exact multiples of 256 float4s.
__global__ void prep_kernel(const float* __restrict__ hidden,
                            const float* __restrict__ Wq,
                            const float* __restrict__ Wk,
                            const float* __restrict__ Wv,
                            const float* __restrict__ mask,
                            ushort* __restrict__ Xb,
                            ushort* __restrict__ Wqb,
                            ushort* __restrict__ Wkb,
                            ushort* __restrict__ Wvb,
                            float* __restrict__ maskL){
  const int bid = blockIdx.x;
  if (bid < 6144 + 3*576){
    const float* src; ushort* dst; int i;
    if (bid < 6144){
      src = hidden; dst = Xb;  i = bid*256 + threadIdx.x;
    } else if (bid < 6144 + 576){
      src = Wq; dst = Wqb;     i = (bid - 6144)*256 + threadIdx.x;
    } else if (bid < 6144 + 1152){
      src = Wk; dst = Wkb;     i = (bid - 6720)*256 + threadIdx.x;
    } else {
      src = Wv; dst = Wvb;     i = (bid - 7296)*256 + threadIdx.x;
    }
    float4 v = ((const float4*)src)[i];
    ushort4 o; o.x = f2bf(v.x); o.y = f2bf(v.y); o.z = f2bf(v.z); o.w = f2bf(v.w);
    ((ushort4*)dst)[i] = o;
  } else {
    int i = (bid - 7872)*256 + threadIdx.x;   // 8 blocks x 256 float4 = 8192 f32
    float4 v = ((const float4*)mask)[i];
    float4 o;
    o.x = v.x * LOG2E; o.y = v.y * LOG2E; o.z = v.z * LOG2E; o.w = v.w * LOG2E;
    ((float4*)maskL)[i] = o;
  }
}

// Fused QKV projection: one launch, grid (64, 18). blockIdx.y/6 selects {Q,K,V}.
__global__ __launch_bounds__(256) void qkv_fused(const ushort* __restrict__ Xb,
                                                 const ushort* __restrict__ Wqb,
                                                 const ushort* __restrict__ Wkb,
                                                 const ushort* __restrict__ Wvb,
                                                 const float* __restrict__ bqp,
                                                 const float* __restrict__ bkp,
                                                 const float* __restrict__ bvp,
                                                 ushort* __restrict__ Qo,
                                                 ushort* __restrict__ Ko,
                                                 ushort* __restrict__ Vto,
                                                 float qscale){
  __shared__ ushort Xs[128*64];
  __shared__ ushort Ws[128*64];
  const int sel = blockIdx.y / 6;
  const int m0 = blockIdx.x * 128, n0 = (blockIdx.y % 6) * 128;
  const ushort* Wb  = (sel == 0) ? Wqb : (sel == 1) ? Wkb : Wvb;
  const float* bias = (sel == 0) ? bqp : (sel == 1) ? bkp : bvp;
  const int tid = threadIdx.x, w = tid >> 6, lane = tid & 63;
  const int r = lane & 15, g = lane >> 4;
  const int wr = (w >> 1) * 64, wc = (w & 1) * 64;
  const int lrow = lane >> 3;
  const int gk = (lane & 7) ^ lrow;
  f32x4 acc[4][4] = {};
  for (int k0 = 0; k0 < 768; k0 += 64){
    #pragma unroll
    for (int p = 0; p < 4; p++){
      int rowb = p*32 + w*8;
      int row = rowb + lrow;
      __builtin_amdgcn_global_load_lds(
        (const uint4*)(Xb + (size_t)(m0+row)*768 + k0 + gk*8),
        (uint4*)((char*)Xs + rowb*128), 16, 0, 0);
      __builtin_amdgcn_global_load_lds(
        (const uint4*)(Wb + (size_t)(n0+row)*768 + k0 + gk*8),
        (uint4*)((char*)Ws + rowb*128), 16, 0, 0);
    }
    __syncthreads();
    #pragma unroll
    for (int ks = 0; ks < 2; ks++){
      short8 af[4], bf[4];
      int bo = ks*64 + g*16;
      #pragma unroll
      for (int i = 0; i < 4; i++){
        int rowa = wr + i*16 + r;
        af[i] = *(const short8*)((char*)Xs + rowa*128 + (bo ^ ((rowa&7)<<4)));
        int rowb2 = wc + i*16 + r;
        bf[i] = *(const short8*)((char*)Ws + rowb2*128 + (bo ^ ((rowb2&7)<<4)));
      }
      #pragma unroll
      for (int i = 0; i < 4; i++)
        #pragma unroll
        for (int j = 0; j < 4; j++)
          acc[i][j] = __builtin_amdgcn_mfma_f32_16x16x32_bf16(af[i], bf[j], acc[i][j], 0,0,0);
    }
    __syncthreads();
  }
  if (sel < 2){
    ushort* Out = sel ? Ko : Qo;
    float scale = sel ? 1.0f : qscale;
    #pragma unroll
    for (int i = 0; i < 4; i++){
      #pragma unroll
      for (int j = 0; j < 4; j++){
        int col = n0 + wc + j*16 + r;
        float bv = bias[col];
        int rowb = m0 + wr + i*16 + g*4;
        #pragma unroll
        for (int q = 0; q < 4; q++)
          Out[(size_t)(rowb+q)*768 + col] = f2bf((acc[i][j][q] + bv) * scale);
      }
    }
  } else {
    #pragma unroll
    for (int i = 0; i < 4; i++){
      #pragma unroll
      for (int j = 0; j < 4; j++){
        int col = n0 + wc + j*16 + r;
        float bv = bias[col];
        int rowb = m0 + wr + i*16 + g*4;
        ushort4 o;
        o.x = f2bf(acc[i][j][0] + bv);
        o.y = f2bf(acc[i][j][1] + bv);
        o.z = f2bf(acc[i][j][2] + bv);
        o.w = f2bf(acc[i][j][3] + bv);
        size_t vrow = (size_t)((rowb >> 12) * 768 + col);
        *(ushort4*)(Vto + vrow * 4096 + (rowb & 4095)) = o;
      }
    }
  }
}

// Flash attention: R12 compute core EXACTLY (online max + defer-max, dbuf LDS,
// split-KV x2). Epilogue: bf16 partials + (m,l).
__global__ __launch_bounds__(256, 3) void flash_attn(const ushort* __restrict__ Qb,
                                                     const ushort* __restrict__ Kb,
                                                     const ushort* __restrict__ Vt,
                                                     const float* __restrict__ maskL,
                                                     ushort* __restrict__ part0,
                                                     ushort* __restrict__ part1,
                                                     float2* __restrict__ lm){
  __shared__ ushort SMEM[16384];  // bytes: K0@0, K1@8192, V0@16384, V1@24576
  const int tid = threadIdx.x, w = tid >> 6, lane = tid & 63;
  const int q = lane & 31, hi = lane >> 5;
  const int swq = (q & 7) << 4;
  const int h = blockIdx.y, b = blockIdx.z;
  const int qt = blockIdx.x >> 1, half = blockIdx.x & 1;
  const int q0 = qt * 128 + w * 32;
  char* sm = (char*)SMEM;

  short8 bq[4];
  {
    const ushort* qp = Qb + (size_t)(b*4096 + q0 + q)*768 + h*64 + hi*8;
    #pragma unroll
    for (int kd = 0; kd < 4; kd++) bq[kd] = *(const short8*)(qp + 16*kd);
  }
  const ushort* Kbase = Kb + (size_t)(b*4096 + half*2048)*768 + h*64;
  const ushort* Vbase = Vt + (size_t)(b*768 + h*64)*4096 + half*2048;

  const int row0 = tid >> 3, cir = tid & 7;
  const int row1 = row0 + 32;
  const int wb0 = row0*128 + ((cir*16) ^ ((row0&7)<<4));
  const int wb1 = row1*128 + ((cir*16) ^ ((row1&7)<<4));
  const ushort* kp0 = Kbase + (size_t)row0*768 + cir*8;
  const ushort* kp1 = Kbase + (size_t)row1*768 + cir*8;
  const ushort* vp0 = Vbase + (size_t)row0*4096 + cir*8;
  const ushort* vp1 = Vbase + (size_t)row1*4096 + cir*8;

  int off4[4];
  #pragma unroll
  for (int kd = 0; kd < 4; kd++)
    off4[kd] = q*128 + ((32*kd + 16*hi) ^ swq);

  // tile0 -> buf0, tile1 -> regs
  uint4 k0r = *(const uint4*)kp0, k1r = *(const uint4*)kp1;
  uint4 v0r = *(const uint4*)vp0, v1r = *(const uint4*)vp1;
  *(uint4*)(sm + wb0) = k0r;           *(uint4*)(sm + wb1) = k1r;
  *(uint4*)(sm + 16384 + wb0) = v0r;   *(uint4*)(sm + 16384 + wb1) = v1r;
  k0r = *(const uint4*)(kp0 + (size_t)64*768);
  k1r = *(const uint4*)(kp1 + (size_t)64*768);
  v0r = *(const uint4*)(vp0 + 64);
  v1r = *(const uint4*)(vp1 + 64);
  __syncthreads();

  F16u c0, c1;
  { f32x16 zz = {}; c0.v = zz; c1.v = zz; }
  float mrun = -1e30f, lrun = 0.f;

  for (int t = 0; t < 32; t++){
    const int tb = (t & 1) << 13;
    const char* kb = sm + tb;
    const char* vb = kb + 16384;
    // QK^T
    __builtin_amdgcn_s_setprio(1);
    f32x16 z0 = {}, z1 = {};
    #pragma unroll
    for (int kd = 0; kd < 4; kd++){
      short8 ak = *(const short8*)(kb + off4[kd]);
      z0 = __builtin_amdgcn_mfma_f32_32x32x16_bf16(ak, bq[kd], z0, 0,0,0);
    }
    #pragma unroll
    for (int kd = 0; kd < 4; kd++){
      short8 ak = *(const short8*)(kb + 4096 + off4[kd]);
      z1 = __builtin_amdgcn_mfma_f32_32x32x16_bf16(ak, bq[kd], z1, 0,0,0);
    }
    __builtin_amdgcn_s_setprio(0);
    F16u s0, s1; s0.v = z0; s1.v = z1;
    // stage t+1 regs -> other buffer
    if (t < 31){
      char* wbuf = sm + (tb ^ 8192);
      *(uint4*)(wbuf + wb0) = k0r;           *(uint4*)(wbuf + wb1) = k1r;
      *(uint4*)(wbuf + 16384 + wb0) = v0r;   *(uint4*)(wbuf + 16384 + wb1) = v1r;
    }
    // issue loads for t+2
    if (t < 30){
      const size_t kn = (size_t)(t+2) * 64;
      k0r = *(const uint4*)(kp0 + kn*768);
      k1r = *(const uint4*)(kp1 + kn*768);
      v0r = *(const uint4*)(vp0 + kn);
      v1r = *(const uint4*)(vp1 + kn);
    }
    // + mask (log2-scaled), packed adds
    const float* mrow = maskL + b*4096 + half*2048 + t*64 + hi*4;
    #pragma unroll
    for (int eq = 0; eq < 4; eq++){
      float4 m0v = *(const float4*)(mrow + eq*8);
      s0.d[2*eq]   = pk_add(s0.d[2*eq],   f2d(m0v.x, m0v.y));
      s0.d[2*eq+1] = pk_add(s0.d[2*eq+1], f2d(m0v.z, m0v.w));
      float4 m1v = *(const float4*)(mrow + 32 + eq*8);
      s1.d[2*eq]   = pk_add(s1.d[2*eq],   f2d(m1v.x, m1v.y));
      s1.d[2*eq+1] = pk_add(s1.d[2*eq+1], f2d(m1v.z, m1v.w));
    }
    // max over 32 in-lane values + lane^32 exchange
    float ma = fmax3(s0.f[0], s0.f[1], s0.f[2]);
    float mb = fmax3(s0.f[3], s0.f[4], s0.f[5]);
    ma = fmax3(ma, s0.f[6], s0.f[7]);
    mb = fmax3(mb, s0.f[8], s0.f[9]);
    ma = fmax3(ma, s0.f[10], s0.f[11]);
    mb = fmax3(mb, s0.f[12], s0.f[13]);
    ma = fmax3(ma, s0.f[14], s0.f[15]);
    mb = fmax3(mb, s1.f[0], s1.f[1]);
    ma = fmax3(ma, s1.f[2], s1.f[3]);
    mb = fmax3(mb, s1.f[4], s1.f[5]);
    ma = fmax3(ma, s1.f[6], s1.f[7]);
    mb = fmax3(mb, s1.f[8], s1.f[9]);
    ma = fmax3(ma, s1.f[10], s1.f[11]);
    mb = fmax3(mb, s1.f[12], s1.f[13]);
    float mt = fmax3(ma, s1.f[14], fmaxf(mb, s1.f[15]));
    mt = fmaxf(mt, __shfl_xor(mt, 32, 64));
    // defer-max (THR = 8*log2e)
    if (!__all(mt <= mrun + 11.5415603f)){
      float mnew = fmaxf(mrun, mt);
      float alpha = exp2_hw(mrun - mnew);
      mrun = mnew;
      lrun *= alpha;
      double al2 = f2d(alpha, alpha);
      #pragma unroll
      for (int i = 0; i < 8; i++){
        c0.d[i] = pk_mul(c0.d[i], al2);
        c1.d[i] = pk_mul(c1.d[i], al2);
      }
    }
    // p = exp2(s - mrun)
    double msub = f2d(-mrun, -mrun);
    #pragma unroll
    for (int i = 0; i < 8; i++){
      s0.d[i] = pk_add(s0.d[i], msub);
      s1.d[i] = pk_add(s1.d[i], msub);
    }
    #pragma unroll
    for (int e = 0; e < 16; e++){
      s0.f[e] = exp2_hw(s0.f[e]);
      s1.f[e] = exp2_hw(s1.f[e]);
    }
    // row-sum via packed tree
    double t00 = pk_add(s0.d[0], s0.d[1]), t01 = pk_add(s0.d[2], s0.d[3]);
    double t02 = pk_add(s0.d[4], s0.d[5]), t03 = pk_add(s0.d[6], s0.d[7]);
    double t10 = pk_add(s1.d[0], s1.d[1]), t11 = pk_add(s1.d[2], s1.d[3]);
    double t12 = pk_add(s1.d[4], s1.d[5]), t13 = pk_add(s1.d[6], s1.d[7]);
    double u0 = pk_add(t00, t01), u1 = pk_add(t02, t03);
    double u2 = pk_add(t10, t11), u3 = pk_add(t12, t13);
    double wsum = pk_add(pk_add(u0, u1), pk_add(u2, u3));
    {
      union { double d; float f[2]; } uw; uw.d = wsum;
      float rs = uw.f[0] + uw.f[1];
      rs += __shfl_xor(rs, 32, 64);
      lrun += rs;
    }
    // pack P (cvt_pk) + permlane32_swap -> PV B-frags
    short8 bp[4];
    {
      uint pw[8];
      #pragma unroll
      for (int u = 0; u < 8; u++) pw[u] = cvtpk_bf16(s0.f[2*u], s0.f[2*u+1]);
      #pragma unroll
      for (int u2 = 0; u2 < 2; u2++){
        uint x0 = pw[4*u2+0], x1 = pw[4*u2+1], x2 = pw[4*u2+2], x3 = pw[4*u2+3];
        asm("v_permlane32_swap_b32 %0, %1" : "+v"(x0), "+v"(x2));
        asm("v_permlane32_swap_b32 %0, %1" : "+v"(x1), "+v"(x3));
        union { uint u[4]; short8 v; } bb;
        bb.u[0] = x0; bb.u[1] = x1; bb.u[2] = x2; bb.u[3] = x3;
        bp[u2] = bb.v;
      }
      #pragma unroll
      for (int u = 0; u < 8; u++) pw[u] = cvtpk_bf16(s1.f[2*u], s1.f[2*u+1]);
      #pragma unroll
      for (int u2 = 0; u2 < 2; u2++){
        uint x0 = pw[4*u2+0], x1 = pw[4*u2+1], x2 = pw[4*u2+2], x3 = pw[4*u2+3];
        asm("v_permlane32_swap_b32 %0, %1" : "+v"(x0), "+v"(x2));
        asm("v_permlane32_swap_b32 %0, %1" : "+v"(x1), "+v"(x3));
        union { uint u[4]; short8 v; } bb;
        bb.u[0] = x0; bb.u[1] = x1; bb.u[2] = x2; bb.u[3] = x3;
        bp[2+u2] = bb.v;
      }
    }
    // PV
    __builtin_amdgcn_s_setprio(1);
    #pragma unroll
    for (int kk = 0; kk < 4; kk++){
      short8 av = *(const short8*)(vb + off4[kk]);
      c0.v = __builtin_amdgcn_mfma_f32_32x32x16_bf16(av, bp[kk], c0.v, 0,0,0);
    }
    #pragma unroll
    for (int kk = 0; kk < 4; kk++){
      short8 av = *(const short8*)(vb + 4096 + off4[kk]);
      c1.v = __builtin_amdgcn_mfma_f32_32x32x16_bf16(av, bp[kk], c1.v, 0,0,0);
    }
    __builtin_amdgcn_s_setprio(0);
    __syncthreads();
  }
  // epilogue: write UNNORMALIZED bf16 partial ctx + (m,l)
  ushort* part = half ? part1 : part0;
  size_t orow = (size_t)(b*4096 + q0 + q) * 768 + h*64;
  #pragma unroll
  for (int eq = 0; eq < 4; eq++){
    uint2 o;
    o.x = cvtpk_bf16(c0.f[4*eq+0], c0.f[4*eq+1]);
    o.y = cvtpk_bf16(c0.f[4*eq+2], c0.f[4*eq+3]);
    *(uint2*)(part + orow + eq*8 + hi*4) = o;
  }
  #pragma unroll
  for (int eq = 0; eq < 4; eq++){
    uint2 o;
    o.x = cvtpk_bf16(c1.f[4*eq+0], c1.f[4*eq+1]);
    o.y = cvtpk_bf16(c1.f[4*eq+2], c1.f[4*eq+3]);
    *(uint2*)(part + orow + 32 + eq*8 + hi*4) = o;
  }
  if (hi == 0){
    int idx = ((half*2 + b)*12 + h)*4096 + (q0 + q);
    lm[idx] = make_float2(mrun, lrun);
  }
}

// O = (c0*e0 + c1*e1) / (l0*e0 + l1*e1); partials bf16, e_i = exp2(m_i - max).
__global__ void merge_kernel(const ushort* __restrict__ p0, const ushort* __restrict__ p1,
                             const float2* __restrict__ lm, float* __restrict__ out){
  int i = blockIdx.x * 256 + threadIdx.x;     // float4 index
  const int nf4 = 2*4096*768/4;
  if (i >= nf4) return;
  int f = i * 4;
  int b = f / (4096*768);
  int rem = f - b*(4096*768);
  int qrow = rem / 768;
  int col = rem - qrow*768;
  int head = col >> 6;
  float2 L0 = lm[((    b)*12 + head)*4096 + qrow];
  float2 L1 = lm[((2 + b)*12 + head)*4096 + qrow];
  float M = fmaxf(L0.x, L1.x);
  float e0 = exp2f(L0.x - M), e1 = exp2f(L1.x - M);
  float inv = 1.0f / (L0.y*e0 + L1.y*e1);
  float s0 = e0 * inv, s1 = e1 * inv;
  uint2 a = ((const uint2*)p0)[i];
  uint2 c = ((const uint2*)p1)[i];
  float4 o;
  o.x = __builtin_bit_cast(float, a.x << 16)         * s0 + __builtin_bit_cast(float, c.x << 16)         * s1;
  o.y = __builtin_bit_cast(float, a.x & 0xffff0000u) * s0 + __builtin_bit_cast(float, c.x & 0xffff0000u) * s1;
  o.z = __builtin_bit_cast(float, a.y << 16)         * s0 + __builtin_bit_cast(float, c.y << 16)         * s1;
  o.w = __builtin_bit_cast(float, a.y & 0xffff0000u) * s0 + __builtin_bit_cast(float, c.y & 0xffff0000u) * s1;
  ((float4*)out)[i] = o;
}

extern "C" void kernel_launch(void* const* d_in, const int* in_sizes, int n_in,
                              void* d_out, int out_size, void* d_ws, size_t ws_size,
                              hipStream_t stream){
  const float* hidden = (const float*)d_in[0];
  const float* mask   = (const float*)d_in[1];
  const float* Wq     = (const float*)d_in[2];
  const float* bq     = (const float*)d_in[3];
  const float* Wk     = (const float*)d_in[4];
  const float* bk     = (const float*)d_in[5];
  const float* Wv     = (const float*)d_in[6];
  const float* bv     = (const float*)d_in[7];
  char* ws = (char*)d_ws;
  ushort* Xb    = (ushort*)(ws);
  ushort* Wqb   = (ushort*)(ws + 12582912);
  ushort* Wkb   = (ushort*)(ws + 13762560);
  ushort* Wvb   = (ushort*)(ws + 14942208);
  ushort* Qb    = (ushort*)(ws + 16121856);
  ushort* Kb    = (ushort*)(ws + 28704768);
  ushort* Vtb   = (ushort*)(ws + 41287680);  // [1536][4096] bf16 transposed V
  float*  maskL = (float*)(ws + 53870592);   // mask * log2e, 8192 f32
  ushort* part0 = (ushort*)(ws + 53903360);  // bf16 partial ctx (half 0), 12.58 MB
  ushort* part1 = (ushort*)(ws + 66486272);  // bf16 partial ctx (half 1), 12.58 MB
  float2* lmbuf = (float2*)(ws + 79069184);  // 2 halves x 2 x 12 x 4096 float2

  // ONE fused elementwise prologue launch (was 5)
  prep_kernel<<<7880, 256, 0, stream>>>(hidden, Wq, Wk, Wv, mask,
                                        Xb, Wqb, Wkb, Wvb, maskL);

  dim3 gg(64, 18);  // y/6 selects Q,K,V
  qkv_fused<<<gg, 256, 0, stream>>>(Xb, Wqb, Wkb, Wvb, bq, bk, bv,
                                    Qb, Kb, Vtb, 0.125f * LOG2E);

  dim3 ga(64, 12, 2);   // blockIdx.x = (qt<<1) | kv_half
  flash_attn<<<ga, 256, 0, stream>>>(Qb, Kb, Vtb, maskL, part0, part1, lmbuf);
  merge_kernel<<<6144, 256, 0, stream>>>(part0, part1, lmbuf, (float*)d_out);
}